// Round 4
// baseline (77480.786 us; speedup 1.0000x reference)
//
#include <hip/hip_runtime.h>
#include <math.h>

#define STEPS 19
#define NEG_SLOPE 0.01f
#define THREADS 256
#define R 8                        // rows per thread: LDS reads amortized over 8 rows
#define ROWS_PER_BLOCK (THREADS * R)
#define NL2E 1.44269504088896340736f   // log2(e); z-weights pre-scaled by -NL2E

__device__ __forceinline__ float lrelu(float x) {
    return fmaxf(x, NEG_SLOPE * x);    // slope<1 => max(x, 0.01x)
}

__device__ __forceinline__ float fast_exp2(float y) {
#if __has_builtin(__builtin_amdgcn_exp2f)
    return __builtin_amdgcn_exp2f(y);  // raw v_exp_f32
#else
    return exp2f(y);
#endif
}

// sigmoid(x) where y = -log2(e)*x was accumulated directly (weights pre-scaled)
__device__ __forceinline__ float sigm_pre(float y) {
    return __builtin_amdgcn_rcpf(1.0f + fast_exp2(y));
}

__global__ __launch_bounds__(THREADS)
__attribute__((amdgpu_waves_per_eu(1, 2)))   // RA budget = 512 VGPR: forbid spill-for-occupancy
void recurrent_kernel(
    const float* __restrict__ w,
    const float* __restrict__ Wh1, const float* __restrict__ bh1,
    const float* __restrict__ Wh2, const float* __restrict__ bh2,
    const float* __restrict__ Wh3, const float* __restrict__ bh3,
    const float* __restrict__ Wz1, const float* __restrict__ bz1,
    const float* __restrict__ Wz2, const float* __restrict__ bz2,
    const float* __restrict__ Wz3, const float* __restrict__ bz3,
    float* __restrict__ out, int nrows)
{
    // Layer-1 packed {W[0][k], W[1][k], b[k], 0} -> one ds_read_b128 per k.
    __shared__ float4 sH1[50];
    __shared__ float4 sZ1[50];          // pre-scaled by -log2(e)
    // W2 as float4 chunks: row k = chunks [5k..5k+4] -> 5x ds_read_b128 per k.
    __shared__ float4 sWh2v[250];
    __shared__ float4 sWz2v[250];       // pre-scaled by -log2(e)
    __shared__ float  sbh2[20]; __shared__ float sbz2[20];   // sbz2 pre-scaled
    __shared__ float2 sWh3[20]; __shared__ float2 sWz3[20];  // sWz3 pre-scaled
    __shared__ float2 sbh3v;    __shared__ float2 sbz3v;     // sbz3 pre-scaled

    const int t = threadIdx.x;
    if (t < 50) {
        sH1[t] = make_float4(Wh1[t], Wh1[50 + t], bh1[t], 0.0f);
        sZ1[t] = make_float4(-NL2E * Wz1[t], -NL2E * Wz1[50 + t], -NL2E * bz1[t], 0.0f);
    }
    if (t < 250) {
        sWh2v[t] = ((const float4*)Wh2)[t];
        float4 z = ((const float4*)Wz2)[t];
        sWz2v[t] = make_float4(-NL2E * z.x, -NL2E * z.y, -NL2E * z.z, -NL2E * z.w);
    }
    if (t < 20) {
        sbh2[t] = bh2[t];
        sbz2[t] = -NL2E * bz2[t];
        sWh3[t] = make_float2(Wh3[2 * t], Wh3[2 * t + 1]);
        sWz3[t] = make_float2(-NL2E * Wz3[2 * t], -NL2E * Wz3[2 * t + 1]);
    }
    if (t == 0) {
        sbh3v = make_float2(bh3[0], bh3[1]);
        sbz3v = make_float2(-NL2E * bz3[0], -NL2E * bz3[1]);
    }
    __syncthreads();

    // Thread t in block b owns rows  b*ROWS_PER_BLOCK + t + j*THREADS, j=0..R-1
    const int base = blockIdx.x * ROWS_PER_BLOCK + t;

    float h0[R], h1[R];
    #pragma unroll
    for (int j = 0; j < R; ++j) {
        const int row = base + j * THREADS;
        if (row < nrows) {
            const float2 w2 = *(const float2*)(w + 2 * (size_t)row);
            h0[j] = w2.x; h1[j] = w2.y;
        } else { h0[j] = 0.0f; h1[j] = 0.0f; }
    }

    for (int s = 0; s < STEPS; ++s) {
        float acc[R][20];

        // ---- h path: fused [2]->[50]->[20], no [50] array ----
        #pragma unroll
        for (int i = 0; i < 20; ++i) {
            const float b = sbh2[i];
            #pragma unroll
            for (int j = 0; j < R; ++j) acc[j][i] = b;
        }
        #pragma unroll
        for (int k = 0; k < 50; ++k) {
            const float4 wk = sH1[k];
            float a[R];
            #pragma unroll
            for (int j = 0; j < R; ++j)
                a[j] = lrelu(fmaf(h1[j], wk.y, fmaf(h0[j], wk.x, wk.z)));
            #pragma unroll
            for (int q = 0; q < 5; ++q) {
                const float4 wq = sWh2v[k * 5 + q];   // 1 LDS b128 -> 4R=32 FMAs
                #pragma unroll
                for (int j = 0; j < R; ++j) {
                    acc[j][4 * q + 0] = fmaf(a[j], wq.x, acc[j][4 * q + 0]);
                    acc[j][4 * q + 1] = fmaf(a[j], wq.y, acc[j][4 * q + 1]);
                    acc[j][4 * q + 2] = fmaf(a[j], wq.z, acc[j][4 * q + 2]);
                    acc[j][4 * q + 3] = fmaf(a[j], wq.w, acc[j][4 * q + 3]);
                }
            }
        }
        // layer h3: [20] -> [2]
        {
            float nh0[R], nh1[R];
            #pragma unroll
            for (int j = 0; j < R; ++j) { nh0[j] = sbh3v.x; nh1[j] = sbh3v.y; }
            #pragma unroll
            for (int i = 0; i < 20; ++i) {
                const float2 w3 = sWh3[i];            // shared across the R rows
                #pragma unroll
                for (int j = 0; j < R; ++j) {
                    const float a = lrelu(acc[j][i]);
                    nh0[j] = fmaf(a, w3.x, nh0[j]);
                    nh1[j] = fmaf(a, w3.y, nh1[j]);
                }
            }
            #pragma unroll
            for (int j = 0; j < R; ++j) { h0[j] = lrelu(nh0[j]); h1[j] = lrelu(nh1[j]); }
        }

        // ---- z path (uses the NEW h); all z-weights pre-scaled by -log2(e) ----
        #pragma unroll
        for (int i = 0; i < 20; ++i) {
            const float b = sbz2[i];
            #pragma unroll
            for (int j = 0; j < R; ++j) acc[j][i] = b;
        }
        #pragma unroll
        for (int k = 0; k < 50; ++k) {
            const float4 wk = sZ1[k];
            float zk[R];
            #pragma unroll
            for (int j = 0; j < R; ++j)
                zk[j] = sigm_pre(fmaf(h1[j], wk.y, fmaf(h0[j], wk.x, wk.z)));
            #pragma unroll
            for (int q = 0; q < 5; ++q) {
                const float4 wq = sWz2v[k * 5 + q];
                #pragma unroll
                for (int j = 0; j < R; ++j) {
                    acc[j][4 * q + 0] = fmaf(zk[j], wq.x, acc[j][4 * q + 0]);
                    acc[j][4 * q + 1] = fmaf(zk[j], wq.y, acc[j][4 * q + 1]);
                    acc[j][4 * q + 2] = fmaf(zk[j], wq.z, acc[j][4 * q + 2]);
                    acc[j][4 * q + 3] = fmaf(zk[j], wq.w, acc[j][4 * q + 3]);
                }
            }
        }
        {
            float zo0[R], zo1[R];
            #pragma unroll
            for (int j = 0; j < R; ++j) { zo0[j] = sbz3v.x; zo1[j] = sbz3v.y; }
            #pragma unroll
            for (int i = 0; i < 20; ++i) {
                const float2 w3 = sWz3[i];
                #pragma unroll
                for (int j = 0; j < R; ++j) {
                    const float zz = sigm_pre(acc[j][i]);
                    zo0[j] = fmaf(zz, w3.x, zo0[j]);
                    zo1[j] = fmaf(zz, w3.y, zo1[j]);
                }
            }
            #pragma unroll
            for (int j = 0; j < R; ++j) {
                const int row = base + j * THREADS;
                if (row < nrows) {
                    float2 o; o.x = sigm_pre(zo0[j]); o.y = sigm_pre(zo1[j]);
                    *(float2*)(out + (size_t)row * (STEPS * 2) + 2 * s) = o;
                }
            }
        }
    }
}

extern "C" void kernel_launch(void* const* d_in, const int* in_sizes, int n_in,
                              void* d_out, int out_size, void* d_ws, size_t ws_size,
                              hipStream_t stream) {
    const float* w   = (const float*)d_in[0];
    const float* Wh1 = (const float*)d_in[1];
    const float* bh1 = (const float*)d_in[2];
    const float* Wh2 = (const float*)d_in[3];
    const float* bh2 = (const float*)d_in[4];
    const float* Wh3 = (const float*)d_in[5];
    const float* bh3 = (const float*)d_in[6];
    const float* Wz1 = (const float*)d_in[7];
    const float* bz1 = (const float*)d_in[8];
    const float* Wz2 = (const float*)d_in[9];
    const float* bz2 = (const float*)d_in[10];
    const float* Wz3 = (const float*)d_in[11];
    const float* bz3 = (const float*)d_in[12];
    float* out = (float*)d_out;

    const int nrows = in_sizes[0] / 2;  // w is [B,2]
    const int blocks = (nrows + ROWS_PER_BLOCK - 1) / ROWS_PER_BLOCK;

    recurrent_kernel<<<blocks, THREADS, 0, stream>>>(
        w, Wh1, bh1, Wh2, bh2, Wh3, bh3,
        Wz1, bz1, Wz2, bz2, Wz3, bz3, out, nrows);
}

// Round 5
// 1280.314 us; speedup vs baseline: 60.5170x; 60.5170x over previous
//
#include <hip/hip_runtime.h>
#include <math.h>

#define STEPS 19
#define THREADS 256
#define L2E 1.44269504088896340736f   // log2(e)

__device__ __forceinline__ float lrelu(float x) {
    return fmaxf(x, 0.01f * x);        // slope<1 => max(x, 0.01x): v_mul + v_max
}

__device__ __forceinline__ float fast_exp2(float y) {
#if __has_builtin(__builtin_amdgcn_exp2f)
    return __builtin_amdgcn_exp2f(y);  // raw v_exp_f32
#else
    return exp2f(y);
#endif
}

__device__ __forceinline__ float sigm(float x) {
    // 1/(1+2^(-x*log2e)): v_mul + v_exp + v_add + v_rcp
    return __builtin_amdgcn_rcpf(1.0f + fast_exp2(-L2E * x));
}

// No __shared__ anywhere: all weight reads are wave-uniform loads from
// __restrict__ kernel args -> backend emits s_load through the scalar/constant
// cache into SGPRs; FMAs consume them as SGPR operands. The LDS pipe (the
// measured bottleneck of rounds 1-2) is not used at all.
__global__ __launch_bounds__(THREADS) void recurrent_kernel(
    const float* __restrict__ w,
    const float* __restrict__ Wh1, const float* __restrict__ bh1,
    const float* __restrict__ Wh2, const float* __restrict__ bh2,
    const float* __restrict__ Wh3, const float* __restrict__ bh3,
    const float* __restrict__ Wz1, const float* __restrict__ bz1,
    const float* __restrict__ Wz2, const float* __restrict__ bz2,
    const float* __restrict__ Wz3, const float* __restrict__ bz3,
    float* __restrict__ out, int nrows)
{
    const int row = blockIdx.x * THREADS + threadIdx.x;
    if (row >= nrows) return;

    const float2 w2 = *(const float2*)(w + 2 * (size_t)row);
    float h0 = w2.x, h1 = w2.y;

    float* __restrict__ orow = out + (size_t)row * (STEPS * 2);

    for (int s = 0; s < STEPS; ++s) {
        float acc[20];

        // ---- h path: fused [2]->[50]->[20] (no [50] array) ----
        #pragma unroll
        for (int i = 0; i < 20; ++i) acc[i] = bh2[i];        // s_load, L2-resident
        #pragma unroll 5
        for (int k = 0; k < 50; ++k) {
            const float a = lrelu(fmaf(h1, Wh1[50 + k], fmaf(h0, Wh1[k], bh1[k])));
            #pragma unroll
            for (int i = 0; i < 20; ++i)
                acc[i] = fmaf(a, Wh2[k * 20 + i], acc[i]);   // v_fmac v, s, v
        }
        // layer h3: [20] -> [2]
        float nh0 = bh3[0], nh1 = bh3[1];
        #pragma unroll
        for (int i = 0; i < 20; ++i) {
            const float a = lrelu(acc[i]);
            nh0 = fmaf(a, Wh3[2 * i], nh0);
            nh1 = fmaf(a, Wh3[2 * i + 1], nh1);
        }
        h0 = lrelu(nh0);
        h1 = lrelu(nh1);

        // ---- z path (uses the NEW h) ----
        #pragma unroll
        for (int i = 0; i < 20; ++i) acc[i] = bz2[i];
        #pragma unroll 5
        for (int k = 0; k < 50; ++k) {
            const float zk = sigm(fmaf(h1, Wz1[50 + k], fmaf(h0, Wz1[k], bz1[k])));
            #pragma unroll
            for (int i = 0; i < 20; ++i)
                acc[i] = fmaf(zk, Wz2[k * 20 + i], acc[i]);
        }
        float zo0 = bz3[0], zo1 = bz3[1];
        #pragma unroll
        for (int i = 0; i < 20; ++i) {
            const float zz = sigm(acc[i]);
            zo0 = fmaf(zz, Wz3[2 * i], zo0);
            zo1 = fmaf(zz, Wz3[2 * i + 1], zo1);
        }

        float2 o; o.x = sigm(zo0); o.y = sigm(zo1);
        *(float2*)(orow + 2 * s) = o;   // 152B/row region stays L2-resident across steps
    }
}

extern "C" void kernel_launch(void* const* d_in, const int* in_sizes, int n_in,
                              void* d_out, int out_size, void* d_ws, size_t ws_size,
                              hipStream_t stream) {
    const float* w   = (const float*)d_in[0];
    const float* Wh1 = (const float*)d_in[1];
    const float* bh1 = (const float*)d_in[2];
    const float* Wh2 = (const float*)d_in[3];
    const float* bh2 = (const float*)d_in[4];
    const float* Wh3 = (const float*)d_in[5];
    const float* bh3 = (const float*)d_in[6];
    const float* Wz1 = (const float*)d_in[7];
    const float* bz1 = (const float*)d_in[8];
    const float* Wz2 = (const float*)d_in[9];
    const float* bz2 = (const float*)d_in[10];
    const float* Wz3 = (const float*)d_in[11];
    const float* bz3 = (const float*)d_in[12];
    float* out = (float*)d_out;

    const int nrows = in_sizes[0] / 2;  // w is [B,2]
    const int blocks = (nrows + THREADS - 1) / THREADS;

    recurrent_kernel<<<blocks, THREADS, 0, stream>>>(
        w, Wh1, bh1, Wh2, bh2, Wh3, bh3,
        Wz1, bz1, Wz2, bz2, Wz3, bz3, out, nrows);
}